// Round 1
// baseline (2510.814 us; speedup 1.0000x reference)
//
#include <hip/hip_runtime.h>
#include <stdint.h>

#define T_TOTAL 32
#define BATCH   1024
#define INDIM   784
#define HDIM    4096
#define OUTDIM  10
#define BH      (BATCH * HDIM)      // 4,194,304
#define WORDS_PER_T (BH / 64)       // 65,536 u64 words per timestep

// ---------------- W2 transpose: W2[10][4096] -> W2T[4096][10] ----------------
__global__ void k_transpose_w2(const float* __restrict__ W2, float* __restrict__ W2T) {
    int i = blockIdx.x * 256 + threadIdx.x;   // over 40960
    if (i < HDIM * OUTDIM) {
        int h = i / OUTDIM, o = i % OUTDIM;
        W2T[i] = W2[o * HDIM + h];
    }
}

// ---------------- GEMM: Z[m][n] = sum_k A[m][k] * B[n][k] ----------------
// A: [M][784] (x_seq chunk rows, row-major, K contiguous)
// B: W1 [4096][784] (row-major, K contiguous)  -> "NT" gemm, dot-product form
// Tiles: BM=BN=128, BK=16, 256 threads, 8x8 micro-tile per thread.
// fp32 VALU (no fp32 MFMA on CDNA4). Sequential-k accumulation order.
__global__ __launch_bounds__(256) void k_gemm(const float* __restrict__ A,
                                              const float* __restrict__ B,
                                              float* __restrict__ Z) {
    __shared__ float As[16][132];   // [k][m], +4 pad
    __shared__ float Bs[16][132];   // [k][n], +4 pad

    const int tid = threadIdx.x;
    const int tr  = tid >> 4;          // 0..15 (m-dir)
    const int tc  = tid & 15;          // 0..15 (n-dir)
    const int lr  = tid >> 2;          // 0..63 staging row
    const int lk  = (tid & 3) << 2;    // 0,4,8,12 staging k offset

    const float* Ag = A + (size_t)(blockIdx.x * 128) * INDIM;
    const float* Bg = B + (size_t)(blockIdx.y * 128) * INDIM;

    float acc[8][8] = {};

    for (int k0 = 0; k0 < INDIM; k0 += 16) {
        float4 a0 = *(const float4*)(Ag + (size_t)lr        * INDIM + k0 + lk);
        float4 a1 = *(const float4*)(Ag + (size_t)(lr + 64) * INDIM + k0 + lk);
        float4 b0 = *(const float4*)(Bg + (size_t)lr        * INDIM + k0 + lk);
        float4 b1 = *(const float4*)(Bg + (size_t)(lr + 64) * INDIM + k0 + lk);
        __syncthreads();   // previous iteration's LDS reads complete
        As[lk+0][lr]    = a0.x; As[lk+1][lr]    = a0.y; As[lk+2][lr]    = a0.z; As[lk+3][lr]    = a0.w;
        As[lk+0][lr+64] = a1.x; As[lk+1][lr+64] = a1.y; As[lk+2][lr+64] = a1.z; As[lk+3][lr+64] = a1.w;
        Bs[lk+0][lr]    = b0.x; Bs[lk+1][lr]    = b0.y; Bs[lk+2][lr]    = b0.z; Bs[lk+3][lr]    = b0.w;
        Bs[lk+0][lr+64] = b1.x; Bs[lk+1][lr+64] = b1.y; Bs[lk+2][lr+64] = b1.z; Bs[lk+3][lr+64] = b1.w;
        __syncthreads();
#pragma unroll
        for (int kk = 0; kk < 16; ++kk) {
            float4 av0 = *(const float4*)&As[kk][tr * 8];
            float4 av1 = *(const float4*)&As[kk][tr * 8 + 4];
            float4 bv0 = *(const float4*)&Bs[kk][tc * 8];
            float4 bv1 = *(const float4*)&Bs[kk][tc * 8 + 4];
            float av[8] = {av0.x, av0.y, av0.z, av0.w, av1.x, av1.y, av1.z, av1.w};
            float bv[8] = {bv0.x, bv0.y, bv0.z, bv0.w, bv1.x, bv1.y, bv1.z, bv1.w};
#pragma unroll
            for (int i = 0; i < 8; ++i)
#pragma unroll
                for (int j = 0; j < 8; ++j)
                    acc[i][j] = fmaf(av[i], bv[j], acc[i][j]);
        }
    }

    const int m0 = blockIdx.x * 128 + tr * 8;
    const int n0 = blockIdx.y * 128 + tc * 8;
#pragma unroll
    for (int i = 0; i < 8; ++i) {
        float4 c0 = {acc[i][0], acc[i][1], acc[i][2], acc[i][3]};
        float4 c1 = {acc[i][4], acc[i][5], acc[i][6], acc[i][7]};
        *(float4*)(Z + (size_t)(m0 + i) * HDIM + n0)     = c0;
        *(float4*)(Z + (size_t)(m0 + i) * HDIM + n0 + 4) = c1;
    }
}

// ---------------- Layer-1 IF recurrence: per (b,h) chain over t ----------------
// v += Z; s = v>=1; emit bit; v = s ? 0 : v.   Bits packed per wave via ballot.
__global__ __launch_bounds__(256) void k_layer1(const float* __restrict__ Z,
                                                float* __restrict__ v1s,
                                                uint64_t* __restrict__ S1,
                                                int Tc, int first) {
    const size_t i = (size_t)blockIdx.x * 256 + threadIdx.x;   // < BH
    float v = first ? 0.0f : v1s[i];
    const int lane = threadIdx.x & 63;
    const size_t word = i >> 6;
    for (int t = 0; t < Tc; ++t) {
        float z = Z[(size_t)t * BH + i];
        v += z;
        bool s = (v >= 1.0f);
        unsigned long long m = __ballot(s);
        if (lane == 0) S1[(size_t)t * WORDS_PER_T + word] = m;
        if (s) v = 0.0f;
    }
    v1s[i] = v;
}

// ---------------- Layer-2 partial sums from spike bitmask ----------------
// grid: (rows/256, 4 h-splits). Each thread: one (t,b) row, 1024 h's.
// part[hs][row][o] = sum over its h-slice of s1 * W2T[h][o]
__global__ __launch_bounds__(256) void k_layer2_partial(const uint64_t* __restrict__ S1,
                                                        const float* __restrict__ W2T,
                                                        float* __restrict__ part,
                                                        int rowsTotal) {
    __shared__ float w[1024][10];   // 40 KB
    const int hs = blockIdx.y;
    for (int i = threadIdx.x; i < 1024 * 10; i += 256)
        w[i / 10][i % 10] = W2T[hs * 1024 * 10 + i];
    __syncthreads();

    const int row = blockIdx.x * 256 + threadIdx.x;   // rowsTotal is a multiple of 256
    // row = t*1024 + b ; word index = t*65536 + b*64 + hs*16  ==  row*64 + hs*16
    const uint64_t* wp = S1 + (size_t)row * 64 + hs * 16;
    float acc[10] = {};
    for (int wi = 0; wi < 16; ++wi) {
        uint64_t m = wp[wi];
        while (m) {
            int bit = __builtin_ctzll(m);
            m &= m - 1;
            int hl = wi * 64 + bit;
#pragma unroll
            for (int o = 0; o < 10; ++o) acc[o] += w[hl][o];
        }
    }
    float* p = part + ((size_t)hs * rowsTotal + row) * 10;
#pragma unroll
    for (int o = 0; o < 10; ++o) p[o] = acc[o];
}

// ---------------- Layer-2 IF recurrence + spike record ----------------
// 10240 independent (b,o) chains.
__global__ __launch_bounds__(256) void k_layer2_rec(const float* __restrict__ part,
                                                    float* __restrict__ v2s,
                                                    float* __restrict__ recs,
                                                    float* __restrict__ out,
                                                    int Tc, int first, int last) {
    const int i = blockIdx.x * 256 + threadIdx.x;
    if (i >= BATCH * OUTDIM) return;
    float v   = first ? 0.0f : v2s[i];
    float rec = first ? 0.0f : recs[i];
    const int rowsTotal = Tc * BATCH;
    const int b = i / OUTDIM, o = i % OUTDIM;
    for (int t = 0; t < Tc; ++t) {
        const int r = t * BATCH + b;
        float sig = 0.0f;
#pragma unroll
        for (int hs = 0; hs < 4; ++hs)
            sig += part[((size_t)hs * rowsTotal + r) * 10 + o];
        v += sig;
        bool s = (v >= 1.0f);
        rec += s ? 1.0f : 0.0f;
        if (s) v = 0.0f;
    }
    v2s[i] = v;
    recs[i] = rec;
    if (last) out[i] = rec;
}

// ---------------- launch ----------------
extern "C" void kernel_launch(void* const* d_in, const int* in_sizes, int n_in,
                              void* d_out, int out_size, void* d_ws, size_t ws_size,
                              hipStream_t stream) {
    (void)in_sizes; (void)n_in; (void)out_size;
    const float* x  = (const float*)d_in[0];   // [32][1024][784]
    const float* W1 = (const float*)d_in[1];   // [4096][784]
    const float* W2 = (const float*)d_in[2];   // [10][4096]
    float* out = (float*)d_out;                // [1024][10]

    // ws layout: W2T | v1 state | v2 state | rec state | Z chunk | S1 chunk | part chunk
    const size_t szW2T  = (size_t)HDIM * OUTDIM * 4;          // 163,840
    const size_t szV1   = (size_t)BH * 4;                     // 16,777,216
    const size_t szV2   = (size_t)BATCH * OUTDIM * 4;         // 40,960
    const size_t szRec  = szV2;
    const size_t base   = szW2T + szV1 + szV2 + szRec;        // 17,022,976
    const size_t perT   = (size_t)BH * 4                      // Z per step
                        + (size_t)WORDS_PER_T * 8             // S1 per step
                        + (size_t)4 * BATCH * OUTDIM * 4;     // part per step
    int Tc = 1;
    const int cands[6] = {32, 16, 8, 4, 2, 1};
    for (int ci = 0; ci < 6; ++ci) {
        if (base + (size_t)cands[ci] * perT <= ws_size) { Tc = cands[ci]; break; }
    }

    char* p = (char*)d_ws;
    float*    W2T  = (float*)p;     p += szW2T;
    float*    v1s  = (float*)p;     p += szV1;
    float*    v2s  = (float*)p;     p += szV2;
    float*    recs = (float*)p;     p += szRec;
    float*    Z    = (float*)p;     p += (size_t)Tc * BH * 4;
    uint64_t* S1   = (uint64_t*)p;  p += (size_t)Tc * WORDS_PER_T * 8;
    float*    part = (float*)p;

    k_transpose_w2<<<(HDIM * OUTDIM + 255) / 256, 256, 0, stream>>>(W2, W2T);

    const int nch = T_TOTAL / Tc;
    for (int c = 0; c < nch; ++c) {
        const float* Ac = x + (size_t)c * Tc * BATCH * INDIM;
        k_gemm<<<dim3(Tc * 8, HDIM / 128), 256, 0, stream>>>(Ac, W1, Z);
        k_layer1<<<BH / 256, 256, 0, stream>>>(Z, v1s, S1, Tc, c == 0);
        k_layer2_partial<<<dim3(Tc * 4, 4), 256, 0, stream>>>(S1, W2T, part, Tc * BATCH);
        k_layer2_rec<<<(BATCH * OUTDIM + 255) / 256, 256, 0, stream>>>(
            part, v2s, recs, out, Tc, c == 0, c == nch - 1);
    }
}